// Round 7
// baseline (214.985 us; speedup 1.0000x reference)
//
#include <hip/hip_runtime.h>
#include <stdint.h>

#define BB 2
#define TT 2048
#define CC 1024
#define HH 16
#define DD 64
#define MM (BB*TT)   // 4096

typedef unsigned short u16;
typedef __attribute__((ext_vector_type(8))) short short8;
typedef __attribute__((ext_vector_type(4))) float float4v;
typedef __attribute__((ext_vector_type(16))) float f32x16;
typedef __attribute__((ext_vector_type(4))) unsigned short ushort4v;

typedef const __attribute__((address_space(1))) void* gas_t;
typedef __attribute__((address_space(3))) void* las_t;

__device__ __forceinline__ u16 f2bf(float f) {
  union { float f; uint32_t u; } v; v.f = f;
  uint32_t u = v.u;
  return (u16)((u + 0x7FFFu + ((u >> 16) & 1)) >> 16);
}

__device__ __forceinline__ uint32_t cvtpk(float lo, float hi) {
  uint32_t r;
  asm("v_cvt_pk_bf16_f32 %0, %1, %2" : "=v"(r) : "v"(lo), "v"(hi));
  return r;
}

__device__ __forceinline__ void gld_lds16(const void* g, void* l) {
  __builtin_amdgcn_global_load_lds((gas_t)g, (las_t)l, 16, 0, 0);
}

// ---------------- convert x (fp32 -> bf16) ----------------
__global__ __launch_bounds__(256) void k_convert_x(const float* __restrict__ x, u16* __restrict__ xb) {
  int i = (blockIdx.x * 256 + threadIdx.x) * 4;
  float4v v = *(const float4v*)(x + i);
  ushort4v o;
  o[0] = f2bf(v[0]); o[1] = f2bf(v[1]); o[2] = f2bf(v[2]); o[3] = f2bf(v[3]);
  *(ushort4v*)(xb + i) = o;
}

// ---------------- transpose weights (fp32 [k][n] -> bf16 [n][k]) ----------------
__global__ __launch_bounds__(256) void k_transpose_w(const float* __restrict__ Wq, const float* __restrict__ Wk,
                                                     const float* __restrict__ Wv, const float* __restrict__ Wo,
                                                     u16* __restrict__ WT) {
  __shared__ u16 tile[64][72];
  int which = blockIdx.y;
  const float* W = (which == 0) ? Wq : (which == 1) ? Wk : (which == 2) ? Wv : Wo;
  u16* out = WT + (size_t)which * CC * CC;
  int tr = (blockIdx.x >> 4) * 64, tc = (blockIdx.x & 15) * 64;
#pragma unroll
  for (int i = 0; i < 16; ++i) {
    int e = i * 256 + threadIdx.x;
    int r = e >> 6, c = e & 63;
    tile[r][c] = f2bf(W[(size_t)(tr + r) * CC + tc + c]);
  }
  __syncthreads();
#pragma unroll
  for (int i = 0; i < 16; ++i) {
    int e = i * 256 + threadIdx.x;
    int cc2 = e >> 6, rr = e & 63;
    out[(size_t)(tc + cc2) * CC + tr + rr] = tile[rr][cc2];
  }
}

// ---------------- QKV projection GEMM ----------------
// p=0/1: Y[t][n] (Q pre-scaled). p=2: swapped operands -> C=[n][t] so the
// Vt [b,h,d,t] store is 32B-contiguous segments (was 64x8B scatter).
__global__ __launch_bounds__(256, 2) void k_qkv_gemm(
    const u16* __restrict__ xb, const u16* __restrict__ WTall,
    const float* __restrict__ bq, const float* __restrict__ bk, const float* __restrict__ bv,
    u16* __restrict__ Qw, u16* __restrict__ Kw, u16* __restrict__ Vtw) {
  __shared__ u16 Al[2][128 * 32];
  __shared__ u16 Bl[2][128 * 32];
  int p = blockIdx.y;
  const u16* WT = WTall + (size_t)p * (CC * CC);
  const float* bias = (p == 0) ? bq : (p == 1) ? bk : bv;
  int m0 = (blockIdx.x >> 3) * 128;
  int n0 = (blockIdx.x & 7) * 128;
  int tid = threadIdx.x;
  int lane = tid & 63, wave = tid >> 6;
  int wr = wave >> 1, wc = wave & 1;

  float4v acc[4][4];
#pragma unroll
  for (int i = 0; i < 4; ++i)
#pragma unroll
    for (int j = 0; j < 4; ++j) acc[i][j] = float4v{0.f, 0.f, 0.f, 0.f};

  auto stage = [&](int buf, int kt) {
    int k0 = kt * 32;
#pragma unroll
    for (int it = 0; it < 2; ++it) {
      int fc = tid + it * 256;
      int r = fc >> 2, c = fc & 3;
      int cg = c ^ ((r >> 1) & 3);
      const u16* gA = xb + (size_t)(m0 + r) * CC + k0 + cg * 8;
      const u16* gB = WT + (size_t)(n0 + r) * CC + k0 + cg * 8;
      char* lA = (char*)&Al[buf][0] + (wave * 64 + it * 256) * 16;
      char* lB = (char*)&Bl[buf][0] + (wave * 64 + it * 256) * 16;
      gld_lds16(gA, lA);
      gld_lds16(gB, lB);
    }
  };

  stage(0, 0);
  __syncthreads();
  int buf = 0;
  for (int kt = 0; kt < 32; ++kt) {
    if (kt + 1 < 32) stage(buf ^ 1, kt + 1);
    short8 af[4], bfr[4];
#pragma unroll
    for (int mf = 0; mf < 4; ++mf) {
      int row = wr * 64 + mf * 16 + (lane & 15);
      int cs = (lane >> 4) ^ ((row >> 1) & 3);
      af[mf] = *(const short8*)((const char*)&Al[buf][0] + row * 64 + cs * 16);
    }
#pragma unroll
    for (int nf = 0; nf < 4; ++nf) {
      int row = wc * 64 + nf * 16 + (lane & 15);
      int cs = (lane >> 4) ^ ((row >> 1) & 3);
      bfr[nf] = *(const short8*)((const char*)&Bl[buf][0] + row * 64 + cs * 16);
    }
    if (p == 2) {
#pragma unroll
      for (int mf = 0; mf < 4; ++mf)
#pragma unroll
        for (int nf = 0; nf < 4; ++nf)
          acc[mf][nf] = __builtin_amdgcn_mfma_f32_16x16x32_bf16(bfr[nf], af[mf], acc[mf][nf], 0, 0, 0);
    } else {
#pragma unroll
      for (int mf = 0; mf < 4; ++mf)
#pragma unroll
        for (int nf = 0; nf < 4; ++nf)
          acc[mf][nf] = __builtin_amdgcn_mfma_f32_16x16x32_bf16(af[mf], bfr[nf], acc[mf][nf], 0, 0, 0);
    }
    __syncthreads();
    buf ^= 1;
  }

  const float QSCALE = 0.125f * 1.44269504088896340736f;
  if (p == 2) {
    // C[row = n-local][col = t-local]: store Vt[b,h,d,t] with t contiguous
#pragma unroll
    for (int mf = 0; mf < 4; ++mf) {
#pragma unroll
      for (int nf = 0; nf < 4; ++nf) {
        int m_ = m0 + wr * 64 + mf * 16 + (lane & 15);
        int b_ = m_ >> 11, t_ = m_ & 2047;
#pragma unroll
        for (int i = 0; i < 4; ++i) {
          int nn = n0 + wc * 64 + nf * 16 + (lane >> 4) * 4 + i;
          float bval = bias[nn];
          int h_ = nn >> 6, dd = nn & 63;
          Vtw[((size_t)(b_ * HH + h_) * DD + dd) * TT + t_] = f2bf(acc[mf][nf][i] + bval);
        }
      }
    }
  } else {
#pragma unroll
    for (int mf = 0; mf < 4; ++mf) {
#pragma unroll
      for (int nf = 0; nf < 4; ++nf) {
        int n = n0 + wc * 64 + nf * 16 + (lane & 15);
        float bval = bias[n];
        int rowBase = wr * 64 + mf * 16 + (lane >> 4) * 4;
        int m_ = m0 + rowBase;
        int b_ = m_ >> 11, t_ = m_ & 2047;
        int h_ = n >> 6, dd = n & 63;
        u16* outp = (p == 0) ? Qw : Kw;
        float s = (p == 0) ? QSCALE : 1.0f;
#pragma unroll
        for (int i = 0; i < 4; ++i) {
          outp[((size_t)(b_ * HH + h_) * TT + (t_ + i)) * DD + dd] = f2bf((acc[mf][nf][i] + bval) * s);
        }
      }
    }
  }
}

// ---------------- flash attention (causal), v6 ----------------
// v5 post-mortem: all blocks co-resident -> makespan = heaviest block
// (32 serial tiles, tail at ~1 wave/SIMD). v6: in-block split-KV: 4 waves,
// wq=q-half (32 rows), wk=kv-half; each pair stages its own K/V tiles ->
// max 17 serial tiles. Lane-local merge via LDS; O stored via in-LDS
// transpose (128B segments, was 64x8B scatter). Core compute = v5
// (coalesced gld_lds staging + swapped 32x32x16 MFMA + in-reg softmax).
__global__ __launch_bounds__(256, 2) void k_attn(
    const u16* __restrict__ Qw, const u16* __restrict__ Kw,
    const u16* __restrict__ Vtw, u16* __restrict__ Ow) {
  __shared__ u16 Klds[2][2][64 * 64];   // [kv-pair][dbuf]
  __shared__ u16 Vlds[2][2][64 * 64];
  int bid = blockIdx.x;
  int xcd = bid & 7, rank = bid >> 3;
  int bh = xcd + ((rank & 3) << 3);     // 4 heads per XCD -> K/V L2-resident
  int u = 31 - (rank >> 2);             // heavy q-tiles first
  int tid = threadIdx.x, lane = tid & 63, wave = tid >> 6;
  int wq = wave & 1, wk = wave >> 1;
  int l31 = lane & 31, hi = lane >> 5;
  int b_ = bh >> 4, h_ = bh & 15;
  const u16* Qbase = Qw + (size_t)bh * TT * DD;
  const u16* Kbase = Kw + (size_t)bh * TT * DD;
  const u16* Vbase = Vtw + (size_t)bh * DD * TT;
  int q32 = u * 64 + wq * 32;
  int nt = u + 1;
  int hA = (nt + 1) >> 1;               // pair0: tiles [0, hA)
  int hB = nt >> 1;                     // pair1: tiles [hA, nt)
  int tbase = wk ? hA : 0;
  int myn = wk ? hB : hA;
  int ptid = wq * 64 + lane;            // pair-local tid
  int sr = ptid >> 3, sc = ptid & 7;
  int swz = l31 & 7;

  short8 qf[4];
#pragma unroll
  for (int ks = 0; ks < 4; ++ks)
    qf[ks] = *(const short8*)(Qbase + (size_t)(q32 + l31) * DD + ks * 16 + hi * 8);

  f32x16 acc0, acc1;
#pragma unroll
  for (int r = 0; r < 16; ++r) { acc0[r] = 0.f; acc1[r] = 0.f; }
  float mrun = -1e30f, lrun = 0.f;

  auto stageKV = [&](int t, int sb) {
    int kv0 = t * 64;
#pragma unroll
    for (int rd = 0; rd < 4; ++rd) {
      int r = rd * 16 + sr;
      int cg = sc ^ (r & 7);
      const u16* gK = Kbase + (size_t)(kv0 + r) * DD + cg * 8;
      const u16* gV = Vbase + (size_t)r * TT + kv0 + cg * 8;
      char* lK = (char*)&Klds[wk][sb][0] + (rd * 128 + wq * 64) * 16;
      char* lV = (char*)&Vlds[wk][sb][0] + (rd * 128 + wq * 64) * 16;
      gld_lds16(gK, lK);
      gld_lds16(gV, lV);
    }
  };

  if (myn > 0) stageKV(tbase, 0);
  int buf = 0;
  for (int i = 0; i < hA; ++i) {
    __syncthreads();                    // stage(i) visible; buf^1 readers done
    if (i + 1 < myn) stageKV(tbase + i + 1, buf ^ 1);
    if (i < myn) {
      int t = tbase + i;
      int kv0 = t * 64;
      const char* Kb = (const char*)&Klds[wk][buf][0];
      const char* Vb = (const char*)&Vlds[wk][buf][0];

      // S = K * Q^T (swapped): lane holds q=l31; rows kv = 8m+4hi+j (+32 s1)
      f32x16 s0, s1;
#pragma unroll
      for (int r = 0; r < 16; ++r) { s0[r] = 0.f; s1[r] = 0.f; }
#pragma unroll
      for (int ks = 0; ks < 4; ++ks) {
        short8 kf = *(const short8*)(Kb + l31 * 128 + ((2 * ks + hi) ^ swz) * 16);
        s0 = __builtin_amdgcn_mfma_f32_32x32x16_bf16(kf, qf[ks], s0, 0, 0, 0);
      }
#pragma unroll
      for (int ks = 0; ks < 4; ++ks) {
        short8 kf = *(const short8*)(Kb + (l31 + 32) * 128 + ((2 * ks + hi) ^ swz) * 16);
        s1 = __builtin_amdgcn_mfma_f32_32x32x16_bf16(kf, qf[ks], s1, 0, 0, 0);
      }

      if (kv0 + 63 > q32) {
        int qg = q32 + l31;
#pragma unroll
        for (int r = 0; r < 16; ++r) {
          int kvg = kv0 + 8 * (r >> 2) + 4 * hi + (r & 3);
          if (kvg > qg) s0[r] = -1e30f;
          if (kvg + 32 > qg) s1[r] = -1e30f;
        }
      }

      float pm = -1e30f;
#pragma unroll
      for (int r = 0; r < 16; ++r) pm = fmaxf(pm, s0[r]);
#pragma unroll
      for (int r = 0; r < 16; ++r) pm = fmaxf(pm, s1[r]);
      pm = fmaxf(pm, __shfl_xor(pm, 32));

      if (__any(pm > mrun + 8.f)) {     // defer-max (T13)
        float mn = fmaxf(mrun, pm);
        float sc_ = __builtin_exp2f(mrun - mn);
        mrun = mn; lrun *= sc_;
#pragma unroll
        for (int r = 0; r < 16; ++r) { acc0[r] *= sc_; acc1[r] *= sc_; }
      }

      float rs = 0.f;
#pragma unroll
      for (int r = 0; r < 16; ++r) { s0[r] = __builtin_exp2f(s0[r] - mrun); rs += s0[r]; }
#pragma unroll
      for (int r = 0; r < 16; ++r) { s1[r] = __builtin_exp2f(s1[r] - mrun); rs += s1[r]; }
      rs += __shfl_xor(rs, 32);
      lrun += rs;

      uint32_t pk0[4][2], pk1[4][2];
#pragma unroll
      for (int m = 0; m < 4; ++m) {
        pk0[m][0] = cvtpk(s0[4 * m + 0], s0[4 * m + 1]);
        pk0[m][1] = cvtpk(s0[4 * m + 2], s0[4 * m + 3]);
        pk1[m][0] = cvtpk(s1[4 * m + 0], s1[4 * m + 1]);
        pk1[m][1] = cvtpk(s1[4 * m + 2], s1[4 * m + 3]);
      }

#define SLICE(PK, Q1, VS)                                                     \
      {                                                                       \
        uint32_t k0 = hi ? PK[2 * Q1 + 1][0] : PK[2 * Q1][0];                 \
        uint32_t k1 = hi ? PK[2 * Q1 + 1][1] : PK[2 * Q1][1];                 \
        uint32_t t0 = hi ? PK[2 * Q1][0] : PK[2 * Q1 + 1][0];                 \
        uint32_t t1 = hi ? PK[2 * Q1][1] : PK[2 * Q1 + 1][1];                 \
        uint32_t r0 = (uint32_t)__shfl_xor((int)t0, 32);                      \
        uint32_t r1 = (uint32_t)__shfl_xor((int)t1, 32);                      \
        union { uint32_t u[4]; short8 v; } pw;                                \
        pw.u[0] = hi ? r0 : k0; pw.u[1] = hi ? r1 : k1;                       \
        pw.u[2] = hi ? k0 : r0; pw.u[3] = hi ? k1 : r1;                       \
        short8 vf0 = *(const short8*)(Vb + l31 * 128 + ((2 * VS + hi) ^ swz) * 16);       \
        short8 vf1 = *(const short8*)(Vb + (l31 + 32) * 128 + ((2 * VS + hi) ^ swz) * 16);\
        acc0 = __builtin_amdgcn_mfma_f32_32x32x16_bf16(vf0, pw.v, acc0, 0, 0, 0);         \
        acc1 = __builtin_amdgcn_mfma_f32_32x32x16_bf16(vf1, pw.v, acc1, 0, 0, 0);         \
      }
      SLICE(pk0, 0, 0)
      SLICE(pk0, 1, 1)
      SLICE(pk1, 0, 2)
      SLICE(pk1, 1, 3)
#undef SLICE
    }
    buf ^= 1;
  }

  // ---- merge kv-halves (lane-local) ----
  __syncthreads();
  float* Mbuf = (float*)&Klds[0][0][0];
  if (wk == 1) {
    float* mp = Mbuf + (size_t)(wq * 64 + lane) * 37;  // stride 37: conflict-free
    mp[0] = mrun; mp[1] = lrun;
#pragma unroll
    for (int r = 0; r < 16; ++r) { mp[2 + r] = acc0[r]; mp[18 + r] = acc1[r]; }
  }
  __syncthreads();
  if (wk == 0) {
    const float* mp = Mbuf + (size_t)(wq * 64 + lane) * 37;
    float m1 = mp[0], l1 = mp[1];
    float mn = fmaxf(mrun, m1);
    float sA = __builtin_exp2f(mrun - mn);
    float sB = __builtin_exp2f(m1 - mn);
    float inv = 1.f / (lrun * sA + l1 * sB);
    u16* Olds = (u16*)&Vlds[0][0][0] + wq * (32 * 72);  // [q][d] pad 72
#pragma unroll
    for (int m = 0; m < 4; ++m) {
      ushort4v o0, o1;
#pragma unroll
      for (int jj = 0; jj < 4; ++jj) {
        o0[jj] = f2bf((acc0[4 * m + jj] * sA + mp[2 + 4 * m + jj] * sB) * inv);
        o1[jj] = f2bf((acc1[4 * m + jj] * sA + mp[18 + 4 * m + jj] * sB) * inv);
      }
      *(ushort4v*)(Olds + l31 * 72 + 8 * m + 4 * hi) = o0;
      *(ushort4v*)(Olds + l31 * 72 + 32 + 8 * m + 4 * hi) = o1;
    }
    asm volatile("s_waitcnt lgkmcnt(0)" ::: "memory");  // same-wave transpose
#pragma unroll
    for (int rr = 0; rr < 4; ++rr) {
      int q = rr * 8 + (lane >> 3);
      short8 val = *(const short8*)(Olds + q * 72 + (lane & 7) * 8);
      *(short8*)(Ow + ((size_t)(b_ * TT + q32 + q)) * CC + h_ * DD + (lane & 7) * 8) = val;
    }
  }
}

// ---------------- output projection GEMM (bf16 in, fp32 out) ----------------
__global__ __launch_bounds__(256, 2) void k_out_gemm(
    const u16* __restrict__ Ob, const u16* __restrict__ WoT,
    const float* __restrict__ bo, float* __restrict__ out) {
  __shared__ u16 Al[2][128 * 32];
  __shared__ u16 Bl[2][128 * 32];
  int m0 = (blockIdx.x >> 3) * 128;
  int n0 = (blockIdx.x & 7) * 128;
  int tid = threadIdx.x;
  int lane = tid & 63, wave = tid >> 6;
  int wr = wave >> 1, wc = wave & 1;

  float4v acc[4][4];
#pragma unroll
  for (int i = 0; i < 4; ++i)
#pragma unroll
    for (int j = 0; j < 4; ++j) acc[i][j] = float4v{0.f, 0.f, 0.f, 0.f};

  auto stage = [&](int buf, int kt) {
    int k0 = kt * 32;
#pragma unroll
    for (int it = 0; it < 2; ++it) {
      int fc = tid + it * 256;
      int r = fc >> 2, c = fc & 3;
      int cg = c ^ ((r >> 1) & 3);
      const u16* gA = Ob + (size_t)(m0 + r) * CC + k0 + cg * 8;
      const u16* gB = WoT + (size_t)(n0 + r) * CC + k0 + cg * 8;
      char* lA = (char*)&Al[buf][0] + (wave * 64 + it * 256) * 16;
      char* lB = (char*)&Bl[buf][0] + (wave * 64 + it * 256) * 16;
      gld_lds16(gA, lA);
      gld_lds16(gB, lB);
    }
  };

  stage(0, 0);
  __syncthreads();
  int buf = 0;
  for (int kt = 0; kt < 32; ++kt) {
    if (kt + 1 < 32) stage(buf ^ 1, kt + 1);
    short8 af[4], bfr[4];
#pragma unroll
    for (int mf = 0; mf < 4; ++mf) {
      int row = wr * 64 + mf * 16 + (lane & 15);
      int cs = (lane >> 4) ^ ((row >> 1) & 3);
      af[mf] = *(const short8*)((const char*)&Al[buf][0] + row * 64 + cs * 16);
    }
#pragma unroll
    for (int nf = 0; nf < 4; ++nf) {
      int row = wc * 64 + nf * 16 + (lane & 15);
      int cs = (lane >> 4) ^ ((row >> 1) & 3);
      bfr[nf] = *(const short8*)((const char*)&Bl[buf][0] + row * 64 + cs * 16);
    }
#pragma unroll
    for (int mf = 0; mf < 4; ++mf)
#pragma unroll
      for (int nf = 0; nf < 4; ++nf)
        acc[mf][nf] = __builtin_amdgcn_mfma_f32_16x16x32_bf16(af[mf], bfr[nf], acc[mf][nf], 0, 0, 0);
    __syncthreads();
    buf ^= 1;
  }

#pragma unroll
  for (int mf = 0; mf < 4; ++mf)
#pragma unroll
    for (int nf = 0; nf < 4; ++nf) {
      int n = n0 + wc * 64 + nf * 16 + (lane & 15);
      float bval = bo[n];
      int rowBase = m0 + wr * 64 + mf * 16 + (lane >> 4) * 4;
#pragma unroll
      for (int i = 0; i < 4; ++i)
        out[(size_t)(rowBase + i) * CC + n] = acc[mf][nf][i] + bval;
    }
}

extern "C" void kernel_launch(void* const* d_in, const int* in_sizes, int n_in,
                              void* d_out, int out_size, void* d_ws, size_t ws_size,
                              hipStream_t stream) {
  const float* x  = (const float*)d_in[0];
  const float* Wq = (const float*)d_in[1];
  const float* bq = (const float*)d_in[2];
  const float* Wk = (const float*)d_in[3];
  const float* bk = (const float*)d_in[4];
  const float* Wv = (const float*)d_in[5];
  const float* bv = (const float*)d_in[6];
  const float* Wo = (const float*)d_in[7];
  const float* bo = (const float*)d_in[8];
  float* out = (float*)d_out;
  char* ws = (char*)d_ws;
  if (ws_size < (size_t)50331648) return;  // need 48 MB scratch

  u16* xb  = (u16*)(ws);                    // 8 MB
  u16* WT  = (u16*)(ws + 8388608);          // 4 x 2 MB (WqT,WkT,WvT,WoT)
  u16* Qw  = (u16*)(ws + 16777216);         // 8 MB  [b,h,t,d]
  u16* Kw  = (u16*)(ws + 25165824);         // 8 MB  [b,h,t,d]
  u16* Vtw = (u16*)(ws + 33554432);         // 8 MB  [b,h,d,t]
  u16* Ob  = (u16*)(ws + 41943040);         // 8 MB  [b*t, c]

  hipLaunchKernelGGL(k_convert_x, dim3(4096), dim3(256), 0, stream, x, xb);
  hipLaunchKernelGGL(k_transpose_w, dim3(256, 4), dim3(256), 0, stream, Wq, Wk, Wv, Wo, WT);
  hipLaunchKernelGGL(k_qkv_gemm, dim3(256, 3), dim3(256), 0, stream,
                     xb, WT, bq, bk, bv, Qw, Kw, Vtw);
  hipLaunchKernelGGL(k_attn, dim3(1024), dim3(256), 0, stream, Qw, Kw, Vtw, Ob);
  hipLaunchKernelGGL(k_out_gemm, dim3(256), dim3(256), 0, stream,
                     Ob, WT + 3 * 1048576, bo, out);
}